// Round 5
// baseline (66.973 us; speedup 1.0000x reference)
//
#include <hip/hip_runtime.h>

// Problem constants (B=16, C=64, H=64, W=64, K=1024, D=64)
#define HWSZ   4096
#define CCH    64
#define KCB    1024
#define NROW   65536
#define NDTOT  4194304
#define NBLK   2048            // main-path blocks (32 rows each)

typedef __attribute__((ext_vector_type(8))) short short8;
typedef __attribute__((ext_vector_type(4))) float f32x4;

__device__ __forceinline__ unsigned short f2bf_rn(float x) {
    union { float f; unsigned u; } v; v.f = x;
    unsigned r = (v.u + 0x7fffu + ((v.u >> 16) & 1u)) >> 16;
    return (unsigned short)r;
}

// ---------- prep: E -> bf16 rows + he2b[k] = 1.0 + 0.5*||e_k||^2 ----------
__global__ __launch_bounds__(256) void vq_prep(const float* __restrict__ E,
                                               unsigned* __restrict__ Ebf,
                                               float* __restrict__ he2b) {
    int k = blockIdx.x * 256 + threadIdx.x;   // 0..1023
    const float4* ep = (const float4*)(E + (size_t)k * 64);
    float s = 0.f;
    #pragma unroll
    for (int c4 = 0; c4 < 16; ++c4) {
        float4 a = ep[c4];
        s += a.x * a.x + a.y * a.y + a.z * a.z + a.w * a.w;
        Ebf[(size_t)k * 32 + 2 * c4 + 0] = (unsigned)f2bf_rn(a.x) | ((unsigned)f2bf_rn(a.y) << 16);
        Ebf[(size_t)k * 32 + 2 * c4 + 1] = (unsigned)f2bf_rn(a.z) | ((unsigned)f2bf_rn(a.w) << 16);
    }
    he2b[k] = 1.0f + 0.5f * s;
}

// ---------- main: 256 threads / 4 waves; block = 32 rows x 1024 codes ----------
// wave w = all 32 rows x code quarter w. No LDS ops inside the scan loop.
__global__ __launch_bounds__(256, 4) void vq_mfma(const float* __restrict__ z,
                                                  const float* __restrict__ E,
                                                  const short* __restrict__ Ebf,
                                                  const float* __restrict__ he2g,
                                                  float* __restrict__ out,
                                                  float* __restrict__ partial) {
    __shared__ float zs[64][33];       // zs[c][i] = z_flat[n0+i][c]
    __shared__ float he2s[KCB];
    __shared__ unsigned wpack[4][32];
    __shared__ int   rowidx[32];
    __shared__ float wsum[4];

    const int t   = threadIdx.x;       // 0..255
    const int blk = blockIdx.x;        // 0..2047
    const int n0  = blk << 5;          // first of 32 rows
    const int bb  = n0 >> 12;
    const int hw0 = n0 & 4095;
    const float* zb = z + (size_t)bb * CCH * HWSZ + hw0;

    // stage z tile: 512 float4 slots (64 ch x 8), 2 per thread
    #pragma unroll
    for (int q2 = 0; q2 < 2; ++q2) {
        int fi = q2 * 256 + t;
        int c = fi >> 3, s4 = fi & 7;
        float4 v = *(const float4*)(zb + (size_t)c * HWSZ + s4 * 4);
        zs[c][s4 * 4 + 0] = v.x; zs[c][s4 * 4 + 1] = v.y;
        zs[c][s4 * 4 + 2] = v.z; zs[c][s4 * 4 + 3] = v.w;
    }
    #pragma unroll
    for (int q2 = 0; q2 < 4; ++q2) he2s[q2 * 256 + t] = he2g[q2 * 256 + t];
    __syncthreads();

    const int wid  = t >> 6;           // 0..3 = code quarter
    const int lane = t & 63;
    const int col  = lane & 15;
    const int g    = lane >> 4;

    // A-frags for the 2 row-tiles (rows 0-15, 16-31): -z, bf16 truncation
    short8 af[2][2];
    #pragma unroll
    for (int rtl = 0; rtl < 2; ++rtl) {
        const int i = rtl * 16 + col;
        #pragma unroll
        for (int ch = 0; ch < 2; ++ch) {
            short8 a;
            #pragma unroll
            for (int j = 0; j < 8; ++j) {
                union { float f; unsigned u; } v;
                v.f = zs[ch * 32 + g * 8 + j][i];
                a[j] = (short)((v.u >> 16) ^ 0x8000u);
            }
            af[rtl][ch] = a;
        }
    }

    // hoist ALL bias values for this thread's 16 code-tiles out of the loop
    float hvv[16];
    #pragma unroll
    for (int ct = 0; ct < 16; ++ct) hvv[ct] = he2s[wid * 256 + ct * 16 + col];

    float pk[2][4];
    #pragma unroll
    for (int rtl = 0; rtl < 2; ++rtl)
        #pragma unroll
        for (int r = 0; r < 4; ++r) pk[rtl][r] = 3.0e38f;

    // B stream: wave's 256-code quarter, 2-deep prefetch, zero LDS in loop
    const short* pB = Ebf + (size_t)(wid * 256 + col) * 64 + g * 8;
    short8 c0 = *(const short8*)(pB);
    short8 c1 = *(const short8*)(pB + 32);
    short8 nx0 = *(const short8*)(pB + 1024);
    short8 nx1 = *(const short8*)(pB + 1024 + 32);

    #pragma unroll
    for (int ct = 0; ct < 16; ++ct) {
        short8 f0 = c0, f1 = c1;
        if (ct < 14) {
            f0 = *(const short8*)(pB + (size_t)(ct + 2) * 1024);
            f1 = *(const short8*)(pB + (size_t)(ct + 2) * 1024 + 32);
        }
        const int code = wid * 256 + ct * 16 + col;      // fits 10 bits
        const float hb = hvv[ct];
        f32x4 hv = {hb, hb, hb, hb};
        #pragma unroll
        for (int rtl = 0; rtl < 2; ++rtl) {
            f32x4 acc = __builtin_amdgcn_mfma_f32_16x16x32_bf16(af[rtl][0], c0, hv, 0, 0, 0);
            acc = __builtin_amdgcn_mfma_f32_16x16x32_bf16(af[rtl][1], c1, acc, 0, 0, 0);
            #pragma unroll
            for (int r = 0; r < 4; ++r) {
                union { float f; unsigned u; } m; m.f = acc[r];  // 1 + 0.5||e||^2 - z.e  (>0)
                m.u = (m.u & 0xFFFFFC00u) | (unsigned)code;      // v_and_or_b32
                pk[rtl][r] = fminf(pk[rtl][r], m.f);             // float-min == uint-min (>0)
            }
        }
        c0 = nx0; c1 = nx1; nx0 = f0; nx1 = f1;
    }

    // reduce across the 16 code-columns
    #pragma unroll
    for (int rtl = 0; rtl < 2; ++rtl) {
        #pragma unroll
        for (int r = 0; r < 4; ++r) {
            float d = pk[rtl][r];
            #pragma unroll
            for (int mask = 1; mask < 16; mask <<= 1)
                d = fminf(d, __shfl_xor(d, mask, 64));
            if (col == 0) {
                union { float f; unsigned u; } b; b.f = d;
                wpack[wid][rtl * 16 + g * 4 + r] = b.u;
            }
        }
    }
    __syncthreads();

    if (t < 32) {   // combine the 4 code-quarter waves
        unsigned u0 = wpack[0][t], u1 = wpack[1][t];
        unsigned u2 = wpack[2][t], u3 = wpack[3][t];
        unsigned m01 = u0 < u1 ? u0 : u1;
        unsigned m23 = u2 < u3 ? u2 : u3;
        unsigned m = m01 < m23 ? m01 : m23;
        rowidx[t] = (int)(m & 1023u);
    }
    __syncthreads();

    // ---- output = E rows (== z + (q - z) to 1 ulp), float4 stores + loss ----
    float lsum = 0.f;
    const int d0i = (t & 15) * 4;
    const int r0  = t >> 4;                  // 0..15
    float* ob = out + (size_t)n0 * 64;
    #pragma unroll
    for (int jj = 0; jj < 2; ++jj) {
        int nl = r0 + 16 * jj;
        int k  = rowidx[nl];                 // uniform per 16-lane group
        float4 qv = *(const float4*)(E + (size_t)k * 64 + d0i);
        float z0 = zs[d0i + 0][nl], z1 = zs[d0i + 1][nl];
        float z2 = zs[d0i + 2][nl], z3 = zs[d0i + 3][nl];
        float e0 = qv.x - z0, e1 = qv.y - z1, e2 = qv.z - z2, e3 = qv.w - z3;
        lsum += e0 * e0 + e1 * e1 + e2 * e2 + e3 * e3;
        *(float4*)(ob + (size_t)nl * 64 + d0i) = qv;
    }

    #pragma unroll
    for (int off = 32; off >= 1; off >>= 1) lsum += __shfl_down(lsum, off, 64);
    if (lane == 0) wsum[wid] = lsum;
    __syncthreads();
    if (t == 0) partial[blk] = (wsum[0] + wsum[1]) + (wsum[2] + wsum[3]);
}

// ---------- fallback fp32 path (round-1, correctness-proven) ----------
__global__ __launch_bounds__(64) void vq_init(float* out) {
    if (threadIdx.x == 0) { out[NDTOT] = 0.0f; out[NDTOT + 1] = 0.0f; }
}

__global__ __launch_bounds__(256, 4) void vq_main_fp32(const float* __restrict__ z,
                                                       const float* __restrict__ E,
                                                       float* __restrict__ out,
                                                       float* __restrict__ partial) {
    __shared__ float zs[64][65];
    __shared__ float e2s[KCB];
    __shared__ float wmin[4][64];
    __shared__ int   widx[4][64];
    __shared__ int   rowidx[64];
    __shared__ float wsum[4];

    const int t   = threadIdx.x;
    const int blk = blockIdx.x;
    const int n0  = blk << 6;
    const int bb  = n0 >> 12;
    const int hw0 = n0 & 4095;
    const float* zb = z + (size_t)bb * CCH * HWSZ + hw0;

    #pragma unroll
    for (int j = 0; j < 16; ++j) {
        int f = t + 256 * j;
        int c = f >> 6, i = f & 63;
        zs[c][i] = zb[(size_t)c * HWSZ + i];
    }
    for (int qq = t; qq < KCB; qq += 256) {
        const float4* ep = (const float4*)(E + (size_t)qq * 64);
        float s0 = 0.f;
        #pragma unroll
        for (int c4 = 0; c4 < 16; ++c4) {
            float4 a = ep[c4];
            s0 += a.x * a.x + a.y * a.y + a.z * a.z + a.w * a.w;
        }
        e2s[qq] = s0;
    }
    __syncthreads();

    const int i   = t & 63;
    const int wid = t >> 6;
    float zr[64];
    #pragma unroll
    for (int c = 0; c < 64; ++c) zr[c] = zs[c][i];

    float best = 3.4e38f;
    int   bi = 0;
    const int k0 = wid << 8;
    const float* Ew = E + (size_t)k0 * 64;
    for (int kk = 0; kk < 256; ++kk) {
        const float4* ek = (const float4*)(Ew + (size_t)kk * 64);
        float d0 = 0.f, d1 = 0.f, d2 = 0.f, d3 = 0.f;
        #pragma unroll
        for (int c4 = 0; c4 < 16; ++c4) {
            float4 a = ek[c4];
            d0 = fmaf(a.x, zr[4 * c4 + 0], d0);
            d1 = fmaf(a.y, zr[4 * c4 + 1], d1);
            d2 = fmaf(a.z, zr[4 * c4 + 2], d2);
            d3 = fmaf(a.w, zr[4 * c4 + 3], d3);
        }
        float dot  = (d0 + d1) + (d2 + d3);
        float dist = fmaf(-2.0f, dot, e2s[k0 + kk]);
        if (dist < best) { best = dist; bi = k0 + kk; }
    }
    wmin[wid][i] = best; widx[wid][i] = bi;
    __syncthreads();
    if (t < 64) {
        float m = wmin[0][t]; int ix = widx[0][t];
        #pragma unroll
        for (int w = 1; w < 4; ++w) {
            float v = wmin[w][t]; int x = widx[w][t];
            if (v < m) { m = v; ix = x; }
        }
        rowidx[t] = ix;
    }
    __syncthreads();

    float lsum = 0.f;
    const size_t base = (size_t)blk * 4096;
    float* oflat = out + base;
    #pragma unroll
    for (int j = 0; j < 16; ++j) {
        int f  = t + 256 * j;
        int nl = f >> 6, d = f & 63;
        int k  = rowidx[nl];
        float qv = E[(size_t)k * 64 + d];
        float zf = zs[d][nl];
        float df = qv - zf;
        lsum += df * df;
        oflat[f] = qv;
    }
    #pragma unroll
    for (int off = 32; off >= 1; off >>= 1) lsum += __shfl_down(lsum, off, 64);
    if (i == 0) wsum[wid] = lsum;
    __syncthreads();
    if (t == 0) {
        float s = (wsum[0] + wsum[1]) + (wsum[2] + wsum[3]);
        if (partial) partial[blk] = s;
        else         atomicAdd(&out[NDTOT + 1], s);
    }
}

__global__ __launch_bounds__(256) void vq_fin(const float* __restrict__ partial,
                                              float* __restrict__ out, int npart) {
    if (npart > 0) {
        __shared__ float ps[256];
        float s = 0.f;
        for (int qq = threadIdx.x; qq < npart; qq += 256) s += partial[qq];
        ps[threadIdx.x] = s;
        __syncthreads();
        for (int st = 128; st >= 1; st >>= 1) {
            if (threadIdx.x < st) ps[threadIdx.x] += ps[threadIdx.x + st];
            __syncthreads();
        }
        if (threadIdx.x == 0) {
            float mse = ps[0] / (float)NDTOT;
            out[NDTOT]     = 0.25f * mse;   // commitment_loss
            out[NDTOT + 1] = mse;           // codebook_loss
        }
    } else {
        if (threadIdx.x == 0) {
            float mse = out[NDTOT + 1] / (float)NDTOT;
            out[NDTOT]     = 0.25f * mse;
            out[NDTOT + 1] = mse;
        }
    }
}

extern "C" void kernel_launch(void* const* d_in, const int* in_sizes, int n_in,
                              void* d_out, int out_size, void* d_ws, size_t ws_size,
                              hipStream_t stream) {
    const float* z = (const float*)d_in[0];
    const float* E = (const float*)d_in[1];
    float* out = (float*)d_out;

    const size_t EBF_BYTES = (size_t)KCB * 64 * 2;                 // 131072
    const size_t need = EBF_BYTES + 4096 + NBLK * sizeof(float);   // Ebf + he2b + partial

    if (ws_size >= need) {
        unsigned* EbfU = (unsigned*)d_ws;
        short* Ebf  = (short*)d_ws;
        float* he2b = (float*)((char*)d_ws + EBF_BYTES);
        float* partial = (float*)((char*)d_ws + EBF_BYTES + 4096);
        hipLaunchKernelGGL(vq_prep, dim3(4), dim3(256), 0, stream, E, EbfU, he2b);
        hipLaunchKernelGGL(vq_mfma, dim3(NBLK), dim3(256), 0, stream,
                           z, E, Ebf, he2b, out, partial);
        hipLaunchKernelGGL(vq_fin, dim3(1), dim3(256), 0, stream, partial, out, NBLK);
    } else {
        float* partial = (ws_size >= KCB * sizeof(float)) ? (float*)d_ws : nullptr;
        int npart = (partial != nullptr) ? KCB : 0;
        hipLaunchKernelGGL(vq_init, dim3(1), dim3(64), 0, stream, out);
        hipLaunchKernelGGL(vq_main_fp32, dim3(1024), dim3(256), 0, stream, z, E, out, partial);
        hipLaunchKernelGGL(vq_fin, dim3(1), dim3(256), 0, stream, partial, out, npart);
    }
}

// Round 6
// 53.694 us; speedup vs baseline: 1.2473x; 1.2473x over previous
//
#include <hip/hip_runtime.h>

// Problem constants (B=16, C=64, H=64, W=64, K=1024, D=64)
#define HWSZ   4096
#define CCH    64
#define KCB    1024
#define NROW   65536
#define NDTOT  4194304
#define NBLK   2048            // main-path blocks (32 rows each)

typedef __attribute__((ext_vector_type(8))) short short8;
typedef __attribute__((ext_vector_type(4))) float f32x4;

__device__ __forceinline__ unsigned short f2bf_rn(float x) {
    union { float f; unsigned u; } v; v.f = x;
    unsigned r = (v.u + 0x7fffu + ((v.u >> 16) & 1u)) >> 16;
    return (unsigned short)r;
}

// ---------- prep: E -> bf16 rows + he2b[k] = 1.0 + 0.5*||e_k||^2 ----------
__global__ __launch_bounds__(256) void vq_prep(const float* __restrict__ E,
                                               unsigned* __restrict__ Ebf,
                                               float* __restrict__ he2b) {
    int k = blockIdx.x * 256 + threadIdx.x;   // 0..1023
    const float4* ep = (const float4*)(E + (size_t)k * 64);
    float s = 0.f;
    #pragma unroll
    for (int c4 = 0; c4 < 16; ++c4) {
        float4 a = ep[c4];
        s += a.x * a.x + a.y * a.y + a.z * a.z + a.w * a.w;
        Ebf[(size_t)k * 32 + 2 * c4 + 0] = (unsigned)f2bf_rn(a.x) | ((unsigned)f2bf_rn(a.y) << 16);
        Ebf[(size_t)k * 32 + 2 * c4 + 1] = (unsigned)f2bf_rn(a.z) | ((unsigned)f2bf_rn(a.w) << 16);
    }
    he2b[k] = 1.0f + 0.5f * s;
}

// ---------- main: 256 threads / 4 waves; block = 32 rows x 1024 codes ----------
// wave w = all 32 rows x code quarter w. No LDS ops inside the scan loop.
// NOTE: launch_bounds arg2 MUST be 2 — arg2=4 caps VGPRs at 64 and spills
// (rounds 3 & 5 both regressed on exactly this; rounds 2 & 4 at arg2=2 were clean).
__global__ __launch_bounds__(256, 2) void vq_mfma(const float* __restrict__ z,
                                                  const float* __restrict__ E,
                                                  const short* __restrict__ Ebf,
                                                  const float* __restrict__ he2g,
                                                  float* __restrict__ out,
                                                  float* __restrict__ partial) {
    __shared__ float zs[64][33];       // zs[c][i] = z_flat[n0+i][c]
    __shared__ float he2s[KCB];
    __shared__ unsigned wpack[4][32];
    __shared__ int   rowidx[32];
    __shared__ float wsum[4];

    const int t   = threadIdx.x;       // 0..255
    const int blk = blockIdx.x;        // 0..2047
    const int n0  = blk << 5;          // first of 32 rows
    const int bb  = n0 >> 12;
    const int hw0 = n0 & 4095;
    const float* zb = z + (size_t)bb * CCH * HWSZ + hw0;

    // stage z tile: 512 float4 slots (64 ch x 8), 2 per thread
    #pragma unroll
    for (int q2 = 0; q2 < 2; ++q2) {
        int fi = q2 * 256 + t;
        int c = fi >> 3, s4 = fi & 7;
        float4 v = *(const float4*)(zb + (size_t)c * HWSZ + s4 * 4);
        zs[c][s4 * 4 + 0] = v.x; zs[c][s4 * 4 + 1] = v.y;
        zs[c][s4 * 4 + 2] = v.z; zs[c][s4 * 4 + 3] = v.w;
    }
    #pragma unroll
    for (int q2 = 0; q2 < 4; ++q2) he2s[q2 * 256 + t] = he2g[q2 * 256 + t];
    __syncthreads();

    const int wid  = t >> 6;           // 0..3 = code quarter
    const int lane = t & 63;
    const int col  = lane & 15;
    const int g    = lane >> 4;

    // A-frags for the 2 row-tiles (rows 0-15, 16-31): -z, bf16 truncation
    short8 af[2][2];
    #pragma unroll
    for (int rtl = 0; rtl < 2; ++rtl) {
        const int i = rtl * 16 + col;
        #pragma unroll
        for (int ch = 0; ch < 2; ++ch) {
            short8 a;
            #pragma unroll
            for (int j = 0; j < 8; ++j) {
                union { float f; unsigned u; } v;
                v.f = zs[ch * 32 + g * 8 + j][i];
                a[j] = (short)((v.u >> 16) ^ 0x8000u);
            }
            af[rtl][ch] = a;
        }
    }

    // hoist ALL bias values for this thread's 16 code-tiles out of the loop
    float hvv[16];
    #pragma unroll
    for (int ct = 0; ct < 16; ++ct) hvv[ct] = he2s[wid * 256 + ct * 16 + col];

    float pk[2][4];
    #pragma unroll
    for (int rtl = 0; rtl < 2; ++rtl)
        #pragma unroll
        for (int r = 0; r < 4; ++r) pk[rtl][r] = 3.0e38f;

    // B stream: wave's 256-code quarter, 2-deep prefetch, zero LDS in loop
    const short* pB = Ebf + (size_t)(wid * 256 + col) * 64 + g * 8;
    short8 c0 = *(const short8*)(pB);
    short8 c1 = *(const short8*)(pB + 32);
    short8 nx0 = *(const short8*)(pB + 1024);
    short8 nx1 = *(const short8*)(pB + 1024 + 32);

    #pragma unroll
    for (int ct = 0; ct < 16; ++ct) {
        short8 f0 = c0, f1 = c1;
        if (ct < 14) {
            f0 = *(const short8*)(pB + (size_t)(ct + 2) * 1024);
            f1 = *(const short8*)(pB + (size_t)(ct + 2) * 1024 + 32);
        }
        const int code = wid * 256 + ct * 16 + col;      // fits 10 bits
        const float hb = hvv[ct];
        f32x4 hv = {hb, hb, hb, hb};
        #pragma unroll
        for (int rtl = 0; rtl < 2; ++rtl) {
            f32x4 acc = __builtin_amdgcn_mfma_f32_16x16x32_bf16(af[rtl][0], c0, hv, 0, 0, 0);
            acc = __builtin_amdgcn_mfma_f32_16x16x32_bf16(af[rtl][1], c1, acc, 0, 0, 0);
            #pragma unroll
            for (int r = 0; r < 4; ++r) {
                union { float f; unsigned u; } m; m.f = acc[r];  // 1 + 0.5||e||^2 - z.e  (>0)
                m.u = (m.u & 0xFFFFFC00u) | (unsigned)code;      // v_and_or_b32
                pk[rtl][r] = fminf(pk[rtl][r], m.f);             // float-min == uint-min (>0)
            }
        }
        c0 = nx0; c1 = nx1; nx0 = f0; nx1 = f1;
    }

    // reduce across the 16 code-columns
    #pragma unroll
    for (int rtl = 0; rtl < 2; ++rtl) {
        #pragma unroll
        for (int r = 0; r < 4; ++r) {
            float d = pk[rtl][r];
            #pragma unroll
            for (int mask = 1; mask < 16; mask <<= 1)
                d = fminf(d, __shfl_xor(d, mask, 64));
            if (col == 0) {
                union { float f; unsigned u; } b; b.f = d;
                wpack[wid][rtl * 16 + g * 4 + r] = b.u;
            }
        }
    }
    __syncthreads();

    if (t < 32) {   // combine the 4 code-quarter waves
        unsigned u0 = wpack[0][t], u1 = wpack[1][t];
        unsigned u2 = wpack[2][t], u3 = wpack[3][t];
        unsigned m01 = u0 < u1 ? u0 : u1;
        unsigned m23 = u2 < u3 ? u2 : u3;
        unsigned m = m01 < m23 ? m01 : m23;
        rowidx[t] = (int)(m & 1023u);
    }
    __syncthreads();

    // ---- output = E rows (== z + (q - z) to 1 ulp), float4 stores + loss ----
    float lsum = 0.f;
    const int d0i = (t & 15) * 4;
    const int r0  = t >> 4;                  // 0..15
    float* ob = out + (size_t)n0 * 64;
    #pragma unroll
    for (int jj = 0; jj < 2; ++jj) {
        int nl = r0 + 16 * jj;
        int k  = rowidx[nl];                 // uniform per 16-lane group
        float4 qv = *(const float4*)(E + (size_t)k * 64 + d0i);
        float z0 = zs[d0i + 0][nl], z1 = zs[d0i + 1][nl];
        float z2 = zs[d0i + 2][nl], z3 = zs[d0i + 3][nl];
        float e0 = qv.x - z0, e1 = qv.y - z1, e2 = qv.z - z2, e3 = qv.w - z3;
        lsum += e0 * e0 + e1 * e1 + e2 * e2 + e3 * e3;
        *(float4*)(ob + (size_t)nl * 64 + d0i) = qv;
    }

    #pragma unroll
    for (int off = 32; off >= 1; off >>= 1) lsum += __shfl_down(lsum, off, 64);
    if (lane == 0) wsum[wid] = lsum;
    __syncthreads();
    if (t == 0) partial[blk] = (wsum[0] + wsum[1]) + (wsum[2] + wsum[3]);
}

// ---------- fallback fp32 path (round-1, correctness-proven) ----------
__global__ __launch_bounds__(64) void vq_init(float* out) {
    if (threadIdx.x == 0) { out[NDTOT] = 0.0f; out[NDTOT + 1] = 0.0f; }
}

__global__ __launch_bounds__(256, 4) void vq_main_fp32(const float* __restrict__ z,
                                                       const float* __restrict__ E,
                                                       float* __restrict__ out,
                                                       float* __restrict__ partial) {
    __shared__ float zs[64][65];
    __shared__ float e2s[KCB];
    __shared__ float wmin[4][64];
    __shared__ int   widx[4][64];
    __shared__ int   rowidx[64];
    __shared__ float wsum[4];

    const int t   = threadIdx.x;
    const int blk = blockIdx.x;
    const int n0  = blk << 6;
    const int bb  = n0 >> 12;
    const int hw0 = n0 & 4095;
    const float* zb = z + (size_t)bb * CCH * HWSZ + hw0;

    #pragma unroll
    for (int j = 0; j < 16; ++j) {
        int f = t + 256 * j;
        int c = f >> 6, i = f & 63;
        zs[c][i] = zb[(size_t)c * HWSZ + i];
    }
    for (int qq = t; qq < KCB; qq += 256) {
        const float4* ep = (const float4*)(E + (size_t)qq * 64);
        float s0 = 0.f;
        #pragma unroll
        for (int c4 = 0; c4 < 16; ++c4) {
            float4 a = ep[c4];
            s0 += a.x * a.x + a.y * a.y + a.z * a.z + a.w * a.w;
        }
        e2s[qq] = s0;
    }
    __syncthreads();

    const int i   = t & 63;
    const int wid = t >> 6;
    float zr[64];
    #pragma unroll
    for (int c = 0; c < 64; ++c) zr[c] = zs[c][i];

    float best = 3.4e38f;
    int   bi = 0;
    const int k0 = wid << 8;
    const float* Ew = E + (size_t)k0 * 64;
    for (int kk = 0; kk < 256; ++kk) {
        const float4* ek = (const float4*)(Ew + (size_t)kk * 64);
        float d0 = 0.f, d1 = 0.f, d2 = 0.f, d3 = 0.f;
        #pragma unroll
        for (int c4 = 0; c4 < 16; ++c4) {
            float4 a = ek[c4];
            d0 = fmaf(a.x, zr[4 * c4 + 0], d0);
            d1 = fmaf(a.y, zr[4 * c4 + 1], d1);
            d2 = fmaf(a.z, zr[4 * c4 + 2], d2);
            d3 = fmaf(a.w, zr[4 * c4 + 3], d3);
        }
        float dot  = (d0 + d1) + (d2 + d3);
        float dist = fmaf(-2.0f, dot, e2s[k0 + kk]);
        if (dist < best) { best = dist; bi = k0 + kk; }
    }
    wmin[wid][i] = best; widx[wid][i] = bi;
    __syncthreads();
    if (t < 64) {
        float m = wmin[0][t]; int ix = widx[0][t];
        #pragma unroll
        for (int w = 1; w < 4; ++w) {
            float v = wmin[w][t]; int x = widx[w][t];
            if (v < m) { m = v; ix = x; }
        }
        rowidx[t] = ix;
    }
    __syncthreads();

    float lsum = 0.f;
    const size_t base = (size_t)blk * 4096;
    float* oflat = out + base;
    #pragma unroll
    for (int j = 0; j < 16; ++j) {
        int f  = t + 256 * j;
        int nl = f >> 6, d = f & 63;
        int k  = rowidx[nl];
        float qv = E[(size_t)k * 64 + d];
        float zf = zs[d][nl];
        float df = qv - zf;
        lsum += df * df;
        oflat[f] = qv;
    }
    #pragma unroll
    for (int off = 32; off >= 1; off >>= 1) lsum += __shfl_down(lsum, off, 64);
    if (i == 0) wsum[wid] = lsum;
    __syncthreads();
    if (t == 0) {
        float s = (wsum[0] + wsum[1]) + (wsum[2] + wsum[3]);
        if (partial) partial[blk] = s;
        else         atomicAdd(&out[NDTOT + 1], s);
    }
}

__global__ __launch_bounds__(256) void vq_fin(const float* __restrict__ partial,
                                              float* __restrict__ out, int npart) {
    if (npart > 0) {
        __shared__ float ps[256];
        float s = 0.f;
        for (int qq = threadIdx.x; qq < npart; qq += 256) s += partial[qq];
        ps[threadIdx.x] = s;
        __syncthreads();
        for (int st = 128; st >= 1; st >>= 1) {
            if (threadIdx.x < st) ps[threadIdx.x] += ps[threadIdx.x + st];
            __syncthreads();
        }
        if (threadIdx.x == 0) {
            float mse = ps[0] / (float)NDTOT;
            out[NDTOT]     = 0.25f * mse;   // commitment_loss
            out[NDTOT + 1] = mse;           // codebook_loss
        }
    } else {
        if (threadIdx.x == 0) {
            float mse = out[NDTOT + 1] / (float)NDTOT;
            out[NDTOT]     = 0.25f * mse;
            out[NDTOT + 1] = mse;
        }
    }
}

extern "C" void kernel_launch(void* const* d_in, const int* in_sizes, int n_in,
                              void* d_out, int out_size, void* d_ws, size_t ws_size,
                              hipStream_t stream) {
    const float* z = (const float*)d_in[0];
    const float* E = (const float*)d_in[1];
    float* out = (float*)d_out;

    const size_t EBF_BYTES = (size_t)KCB * 64 * 2;                 // 131072
    const size_t need = EBF_BYTES + 4096 + NBLK * sizeof(float);   // Ebf + he2b + partial

    if (ws_size >= need) {
        unsigned* EbfU = (unsigned*)d_ws;
        short* Ebf  = (short*)d_ws;
        float* he2b = (float*)((char*)d_ws + EBF_BYTES);
        float* partial = (float*)((char*)d_ws + EBF_BYTES + 4096);
        hipLaunchKernelGGL(vq_prep, dim3(4), dim3(256), 0, stream, E, EbfU, he2b);
        hipLaunchKernelGGL(vq_mfma, dim3(NBLK), dim3(256), 0, stream,
                           z, E, Ebf, he2b, out, partial);
        hipLaunchKernelGGL(vq_fin, dim3(1), dim3(256), 0, stream, partial, out, NBLK);
    } else {
        float* partial = (ws_size >= KCB * sizeof(float)) ? (float*)d_ws : nullptr;
        int npart = (partial != nullptr) ? KCB : 0;
        hipLaunchKernelGGL(vq_init, dim3(1), dim3(64), 0, stream, out);
        hipLaunchKernelGGL(vq_main_fp32, dim3(1024), dim3(256), 0, stream, z, E, out, partial);
        hipLaunchKernelGGL(vq_fin, dim3(1), dim3(256), 0, stream, partial, out, npart);
    }
}

// Round 7
// 44.187 us; speedup vs baseline: 1.5157x; 1.2151x over previous
//
#include <hip/hip_runtime.h>

// Problem constants (B=16, C=64, H=64, W=64, K=1024, D=64)
#define HWSZ   4096
#define CCH    64
#define KCB    1024
#define NROW   65536
#define NDTOT  4194304
#define MBLK   512             // main-path blocks
#define MROWS  128             // rows per block (32 blocks per batch image; no cross-batch tiles)

typedef __attribute__((ext_vector_type(8))) short short8;
typedef __attribute__((ext_vector_type(4))) float f32x4;

__device__ __forceinline__ unsigned short f2bf_rn(float x) {
    union { float f; unsigned u; } v; v.f = x;
    unsigned r = (v.u + 0x7fffu + ((v.u >> 16) & 1u)) >> 16;
    return (unsigned short)r;
}

// ---------- prep: E -> bf16 rows + he2b[k] = 1.0 + 0.5*||e_k||^2 ----------
__global__ __launch_bounds__(256) void vq_prep(const float* __restrict__ E,
                                               unsigned* __restrict__ Ebf,
                                               float* __restrict__ he2b) {
    int k = blockIdx.x * 256 + threadIdx.x;   // 0..1023
    const float4* ep = (const float4*)(E + (size_t)k * 64);
    float s = 0.f;
    #pragma unroll
    for (int c4 = 0; c4 < 16; ++c4) {
        float4 a = ep[c4];
        s += a.x * a.x + a.y * a.y + a.z * a.z + a.w * a.w;
        Ebf[(size_t)k * 32 + 2 * c4 + 0] = (unsigned)f2bf_rn(a.x) | ((unsigned)f2bf_rn(a.y) << 16);
        Ebf[(size_t)k * 32 + 2 * c4 + 1] = (unsigned)f2bf_rn(a.z) | ((unsigned)f2bf_rn(a.w) << 16);
    }
    he2b[k] = 1.0f + 0.5f * s;
}

// ---------- main: 512 blocks x 256 thr; block = 128 rows x 1024 codes ----------
// Wave w holds its 256-code quarter RESIDENT in 128 VGPRs (loaded once);
// the scan loop is pure register MFMA + pack-min: zero memory ops inside.
// NOTE launch_bounds arg2=1: empirically arg2=N caps VGPRs at ~256/N on this
// toolchain (r3/r5 regressions at arg2=4 -> 64 VGPR + spills). B-resident needs ~200.
__global__ __launch_bounds__(256, 1) void vq_mfma(const float* __restrict__ z,
                                                  const float* __restrict__ E,
                                                  const short* __restrict__ Ebf,
                                                  const float* __restrict__ he2g,
                                                  float* __restrict__ out,
                                                  float* __restrict__ partial) {
    __shared__ float zs[64][132];      // zs[c][i] = z_flat[n0+i][c]; 132: rows 16B-aligned
    __shared__ unsigned wpack[4][MROWS];
    __shared__ int   rowidx[MROWS];
    __shared__ float wsum[4];

    const int t   = threadIdx.x;       // 0..255
    const int blk = blockIdx.x;        // 0..511
    const int n0  = blk * MROWS;
    const int bb  = n0 >> 12;
    const int hw0 = n0 & 4095;
    const float* zb = z + (size_t)bb * CCH * HWSZ + hw0;

    const int wid  = t >> 6;           // 0..3 = code quarter
    const int lane = t & 63;
    const int col  = lane & 15;
    const int g    = lane >> 4;

    // ---- resident B-frags: wave's 256 codes, one burst (independent of LDS) ----
    short8 bf0[16], bf1[16];
    const short* pB = Ebf + (size_t)(wid * 256 + col) * 64 + g * 8;
    #pragma unroll
    for (int ct = 0; ct < 16; ++ct) {
        bf0[ct] = *(const short8*)(pB + (size_t)ct * 1024);
        bf1[ct] = *(const short8*)(pB + (size_t)ct * 1024 + 32);
    }
    float hvv[16];
    #pragma unroll
    for (int ct = 0; ct < 16; ++ct) hvv[ct] = he2g[wid * 256 + ct * 16 + col];

    // ---- stage z tile: 64 ch x 128 rows = 2048 float4 slots, 8 per thread ----
    #pragma unroll
    for (int q2 = 0; q2 < 8; ++q2) {
        int fi = q2 * 256 + t;
        int c = fi >> 5, s4 = fi & 31;
        float4 v = *(const float4*)(zb + (size_t)c * HWSZ + s4 * 4);
        *(float4*)(&zs[c][s4 * 4]) = v;
    }
    __syncthreads();

    // ---- 4 row-tiles of 32 rows: register-only scan per tile ----
    for (int ro = 0; ro < 4; ++ro) {
        // A-frags: -z, bf16 truncation + sign flip
        short8 af[2][2];
        #pragma unroll
        for (int rtl = 0; rtl < 2; ++rtl) {
            const int i = ro * 32 + rtl * 16 + col;
            #pragma unroll
            for (int ch = 0; ch < 2; ++ch) {
                short8 a;
                #pragma unroll
                for (int j = 0; j < 8; ++j) {
                    union { float f; unsigned u; } v;
                    v.f = zs[ch * 32 + g * 8 + j][i];
                    a[j] = (short)((v.u >> 16) ^ 0x8000u);
                }
                af[rtl][ch] = a;
            }
        }

        float pk[2][4];
        #pragma unroll
        for (int rtl = 0; rtl < 2; ++rtl)
            #pragma unroll
            for (int r = 0; r < 4; ++r) pk[rtl][r] = 3.0e38f;

        #pragma unroll
        for (int ct = 0; ct < 16; ++ct) {
            const int code = wid * 256 + ct * 16 + col;      // fits 10 bits
            const float hb = hvv[ct];
            f32x4 hv = {hb, hb, hb, hb};
            #pragma unroll
            for (int rtl = 0; rtl < 2; ++rtl) {
                f32x4 acc = __builtin_amdgcn_mfma_f32_16x16x32_bf16(af[rtl][0], bf0[ct], hv, 0, 0, 0);
                acc = __builtin_amdgcn_mfma_f32_16x16x32_bf16(af[rtl][1], bf1[ct], acc, 0, 0, 0);
                #pragma unroll
                for (int r = 0; r < 4; ++r) {
                    union { float f; unsigned u; } m; m.f = acc[r]; // 1+0.5||e||^2 - z.e (>0)
                    m.u = (m.u & 0xFFFFFC00u) | (unsigned)code;     // v_and_or_b32
                    pk[rtl][r] = fminf(pk[rtl][r], m.f);            // float-min == uint-min
                }
            }
        }

        // reduce across the 16 code-columns
        #pragma unroll
        for (int rtl = 0; rtl < 2; ++rtl) {
            #pragma unroll
            for (int r = 0; r < 4; ++r) {
                float d = pk[rtl][r];
                #pragma unroll
                for (int mask = 1; mask < 16; mask <<= 1)
                    d = fminf(d, __shfl_xor(d, mask, 64));
                if (col == 0) {
                    union { float f; unsigned u; } b; b.f = d;
                    wpack[wid][ro * 32 + rtl * 16 + g * 4 + r] = b.u;
                }
            }
        }
    }
    __syncthreads();

    if (t < MROWS) {   // combine the 4 code-quarter waves (positive floats: uint cmp == float cmp)
        unsigned u0 = wpack[0][t], u1 = wpack[1][t];
        unsigned u2 = wpack[2][t], u3 = wpack[3][t];
        unsigned m01 = u0 < u1 ? u0 : u1;
        unsigned m23 = u2 < u3 ? u2 : u3;
        unsigned m = m01 < m23 ? m01 : m23;
        rowidx[t] = (int)(m & 1023u);
    }
    __syncthreads();

    // ---- output = E rows (== z + (q - z) to 1 ulp), float4 coalesced stores + loss ----
    float lsum = 0.f;
    const int d0i = (t & 15) * 4;
    const int r0  = t >> 4;                  // 0..15
    float* ob = out + (size_t)n0 * 64;
    #pragma unroll
    for (int jj = 0; jj < 8; ++jj) {
        int nl = r0 + 16 * jj;
        int k  = rowidx[nl];                 // uniform per 16-lane group
        float4 qv = *(const float4*)(E + (size_t)k * 64 + d0i);
        float z0 = zs[d0i + 0][nl], z1 = zs[d0i + 1][nl];
        float z2 = zs[d0i + 2][nl], z3 = zs[d0i + 3][nl];
        float e0 = qv.x - z0, e1 = qv.y - z1, e2 = qv.z - z2, e3 = qv.w - z3;
        lsum += e0 * e0 + e1 * e1 + e2 * e2 + e3 * e3;
        *(float4*)(ob + (size_t)nl * 64 + d0i) = qv;
    }

    #pragma unroll
    for (int off = 32; off >= 1; off >>= 1) lsum += __shfl_down(lsum, off, 64);
    if (lane == 0) wsum[wid] = lsum;
    __syncthreads();
    if (t == 0) partial[blk] = (wsum[0] + wsum[1]) + (wsum[2] + wsum[3]);
}

// ---------- fallback fp32 path (round-1, correctness-proven) ----------
__global__ __launch_bounds__(64) void vq_init(float* out) {
    if (threadIdx.x == 0) { out[NDTOT] = 0.0f; out[NDTOT + 1] = 0.0f; }
}

__global__ __launch_bounds__(256, 4) void vq_main_fp32(const float* __restrict__ z,
                                                       const float* __restrict__ E,
                                                       float* __restrict__ out,
                                                       float* __restrict__ partial) {
    __shared__ float zs[64][65];
    __shared__ float e2s[KCB];
    __shared__ float wmin[4][64];
    __shared__ int   widx[4][64];
    __shared__ int   rowidx[64];
    __shared__ float wsum[4];

    const int t   = threadIdx.x;
    const int blk = blockIdx.x;
    const int n0  = blk << 6;
    const int bb  = n0 >> 12;
    const int hw0 = n0 & 4095;
    const float* zb = z + (size_t)bb * CCH * HWSZ + hw0;

    #pragma unroll
    for (int j = 0; j < 16; ++j) {
        int f = t + 256 * j;
        int c = f >> 6, i = f & 63;
        zs[c][i] = zb[(size_t)c * HWSZ + i];
    }
    for (int qq = t; qq < KCB; qq += 256) {
        const float4* ep = (const float4*)(E + (size_t)qq * 64);
        float s0 = 0.f;
        #pragma unroll
        for (int c4 = 0; c4 < 16; ++c4) {
            float4 a = ep[c4];
            s0 += a.x * a.x + a.y * a.y + a.z * a.z + a.w * a.w;
        }
        e2s[qq] = s0;
    }
    __syncthreads();

    const int i   = t & 63;
    const int wid = t >> 6;
    float zr[64];
    #pragma unroll
    for (int c = 0; c < 64; ++c) zr[c] = zs[c][i];

    float best = 3.4e38f;
    int   bi = 0;
    const int k0 = wid << 8;
    const float* Ew = E + (size_t)k0 * 64;
    for (int kk = 0; kk < 256; ++kk) {
        const float4* ek = (const float4*)(Ew + (size_t)kk * 64);
        float d0 = 0.f, d1 = 0.f, d2 = 0.f, d3 = 0.f;
        #pragma unroll
        for (int c4 = 0; c4 < 16; ++c4) {
            float4 a = ek[c4];
            d0 = fmaf(a.x, zr[4 * c4 + 0], d0);
            d1 = fmaf(a.y, zr[4 * c4 + 1], d1);
            d2 = fmaf(a.z, zr[4 * c4 + 2], d2);
            d3 = fmaf(a.w, zr[4 * c4 + 3], d3);
        }
        float dot  = (d0 + d1) + (d2 + d3);
        float dist = fmaf(-2.0f, dot, e2s[k0 + kk]);
        if (dist < best) { best = dist; bi = k0 + kk; }
    }
    wmin[wid][i] = best; widx[wid][i] = bi;
    __syncthreads();
    if (t < 64) {
        float m = wmin[0][t]; int ix = widx[0][t];
        #pragma unroll
        for (int w = 1; w < 4; ++w) {
            float v = wmin[w][t]; int x = widx[w][t];
            if (v < m) { m = v; ix = x; }
        }
        rowidx[t] = ix;
    }
    __syncthreads();

    float lsum = 0.f;
    const size_t base = (size_t)blk * 4096;
    float* oflat = out + base;
    #pragma unroll
    for (int j = 0; j < 16; ++j) {
        int f  = t + 256 * j;
        int nl = f >> 6, d = f & 63;
        int k  = rowidx[nl];
        float qv = E[(size_t)k * 64 + d];
        float zf = zs[d][nl];
        float df = qv - zf;
        lsum += df * df;
        oflat[f] = qv;
    }
    #pragma unroll
    for (int off = 32; off >= 1; off >>= 1) lsum += __shfl_down(lsum, off, 64);
    if (i == 0) wsum[wid] = lsum;
    __syncthreads();
    if (t == 0) {
        float s = (wsum[0] + wsum[1]) + (wsum[2] + wsum[3]);
        if (partial) partial[blk] = s;
        else         atomicAdd(&out[NDTOT + 1], s);
    }
}

__global__ __launch_bounds__(256) void vq_fin(const float* __restrict__ partial,
                                              float* __restrict__ out, int npart) {
    if (npart > 0) {
        __shared__ float ps[256];
        float s = 0.f;
        for (int qq = threadIdx.x; qq < npart; qq += 256) s += partial[qq];
        ps[threadIdx.x] = s;
        __syncthreads();
        for (int st = 128; st >= 1; st >>= 1) {
            if (threadIdx.x < st) ps[threadIdx.x] += ps[threadIdx.x + st];
            __syncthreads();
        }
        if (threadIdx.x == 0) {
            float mse = ps[0] / (float)NDTOT;
            out[NDTOT]     = 0.25f * mse;   // commitment_loss
            out[NDTOT + 1] = mse;           // codebook_loss
        }
    } else {
        if (threadIdx.x == 0) {
            float mse = out[NDTOT + 1] / (float)NDTOT;
            out[NDTOT]     = 0.25f * mse;
            out[NDTOT + 1] = mse;
        }
    }
}

extern "C" void kernel_launch(void* const* d_in, const int* in_sizes, int n_in,
                              void* d_out, int out_size, void* d_ws, size_t ws_size,
                              hipStream_t stream) {
    const float* z = (const float*)d_in[0];
    const float* E = (const float*)d_in[1];
    float* out = (float*)d_out;

    const size_t EBF_BYTES = (size_t)KCB * 64 * 2;                 // 131072
    const size_t need = EBF_BYTES + 4096 + MBLK * sizeof(float);   // Ebf + he2b + partial

    if (ws_size >= need) {
        unsigned* EbfU = (unsigned*)d_ws;
        short* Ebf  = (short*)d_ws;
        float* he2b = (float*)((char*)d_ws + EBF_BYTES);
        float* partial = (float*)((char*)d_ws + EBF_BYTES + 4096);
        hipLaunchKernelGGL(vq_prep, dim3(4), dim3(256), 0, stream, E, EbfU, he2b);
        hipLaunchKernelGGL(vq_mfma, dim3(MBLK), dim3(256), 0, stream,
                           z, E, Ebf, he2b, out, partial);
        hipLaunchKernelGGL(vq_fin, dim3(1), dim3(256), 0, stream, partial, out, MBLK);
    } else {
        float* partial = (ws_size >= KCB * sizeof(float)) ? (float*)d_ws : nullptr;
        int npart = (partial != nullptr) ? KCB : 0;
        hipLaunchKernelGGL(vq_init, dim3(1), dim3(64), 0, stream, out);
        hipLaunchKernelGGL(vq_main_fp32, dim3(1024), dim3(256), 0, stream, z, E, out, partial);
        hipLaunchKernelGGL(vq_fin, dim3(1), dim3(256), 0, stream, partial, out, npart);
    }
}

// Round 8
// 31.262 us; speedup vs baseline: 2.1423x; 1.4134x over previous
//
#include <hip/hip_runtime.h>

// Problem constants (B=16, C=64, H=64, W=64, K=1024, D=64)
#define HWSZ   4096
#define CCH    64
#define KCB    1024
#define NROW   65536
#define NDTOT  4194304
#define MBLK   512             // main-path blocks
#define BROWS  128             // rows per block
#define WROWS  32              // rows per wave
#define NCHUNK 16              // codebook chunks
#define CHCODES 64             // codes per chunk (8 KB bf16)

typedef __attribute__((ext_vector_type(8))) short short8;
typedef __attribute__((ext_vector_type(4))) float f32x4;

__device__ __forceinline__ unsigned short f2bf_rn(float x) {
    union { float f; unsigned u; } v; v.f = x;
    unsigned r = (v.u + 0x7fffu + ((v.u >> 16) & 1u)) >> 16;
    return (unsigned short)r;
}

// ---------- prep: E -> bf16 rows (PRE-SWIZZLED: dword ^ ((k&7)<<2)) + he2b ----------
__global__ __launch_bounds__(256) void vq_prep(const float* __restrict__ E,
                                               unsigned* __restrict__ Ebf,
                                               float* __restrict__ he2b) {
    int k = blockIdx.x * 256 + threadIdx.x;   // 0..1023
    const float4* ep = (const float4*)(E + (size_t)k * 64);
    float s = 0.f;
    const unsigned sw = ((unsigned)k & 7u) << 2;   // XOR on dword index (T2 swizzle, prep-side)
    #pragma unroll
    for (int c4 = 0; c4 < 16; ++c4) {
        float4 a = ep[c4];
        s += a.x * a.x + a.y * a.y + a.z * a.z + a.w * a.w;
        unsigned lo = (unsigned)f2bf_rn(a.x) | ((unsigned)f2bf_rn(a.y) << 16);
        unsigned hi = (unsigned)f2bf_rn(a.z) | ((unsigned)f2bf_rn(a.w) << 16);
        unsigned base = (unsigned)k * 32 + 2 * c4;
        Ebf[base ^ sw]       = lo;     // (base+1)^sw == (base^sw)+1 (sw bits >= 2)
        Ebf[(base + 1) ^ sw] = hi;
    }
    he2b[k] = 1.0f + 0.5f * s;
}

// ---------- main: 512 blocks x 256 thr; block = 128 rows; wave = 32 rows x all codes ----
// Codebook streamed through double-buffered LDS chunks (reg-staged, issue-early/
// write-late). A-frags + sum(z^2) direct from global. Loss derived from scores.
// launch_bounds arg2=2 (cap 128): demand ~100, no spill (r3/r5 lesson: arg2=4 -> 64 cap -> spills).
__global__ __launch_bounds__(256, 2) void vq_mfma(const float* __restrict__ z,
                                                  const float* __restrict__ E,
                                                  const short* __restrict__ Ebf,
                                                  const float* __restrict__ he2g,
                                                  float* __restrict__ out,
                                                  float* __restrict__ partial) {
    __shared__ short lbs[2][4096];     // 2 x 8 KB chunk buffers (swizzled image of Ebf)
    __shared__ float wsum[4];

    const int t   = threadIdx.x;       // 0..255
    const int blk = blockIdx.x;        // 0..511
    const int n0  = blk * BROWS;
    const int bb  = n0 >> 12;
    const int wid = t >> 6, lane = t & 63, col = lane & 15, g = lane >> 4;
    const int hwb = (n0 & 4095) + wid * WROWS;      // wave's hw base (within one image)
    const float* zw = z + (size_t)bb * CCH * HWSZ + hwb;

    // ---- A-frags (2 rt x 2 ch) + z^2 partial, direct from global (no LDS, no barrier) ----
    float z2 = 0.f;
    short8 af[2][2];
    #pragma unroll
    for (int rt = 0; rt < 2; ++rt) {
        #pragma unroll
        for (int ch = 0; ch < 2; ++ch) {
            short8 a;
            #pragma unroll
            for (int j = 0; j < 8; ++j) {
                int c = ch * 32 + g * 8 + j;
                float v = zw[(size_t)c * HWSZ + rt * 16 + col];
                z2 = fmaf(v, v, z2);
                union { float f; unsigned u; } uu; uu.f = v;
                a[j] = (short)((uu.u >> 16) ^ 0x8000u);   // -z, bf16 truncation
            }
            af[rt][ch] = a;
        }
    }

    // ---- prologue: stage chunk 0 (32 B/thread) + he2 for chunk 0 ----
    const short8* gB = (const short8*)Ebf;          // 16 B units; swizzle rides along
    short8 sA = gB[t * 2];
    short8 sB = gB[t * 2 + 1];
    float hcur[4];
    #pragma unroll
    for (int q = 0; q < 4; ++q) hcur[q] = he2g[q * 16 + col];
    ((short8*)lbs[0])[t * 2]     = sA;
    ((short8*)lbs[0])[t * 2 + 1] = sB;
    __syncthreads();

    float pk[2][4];
    #pragma unroll
    for (int rt = 0; rt < 2; ++rt)
        #pragma unroll
        for (int r = 0; r < 4; ++r) pk[rt][r] = 3.0e38f;

    // per-lane swizzled LDS read offsets (shorts)
    const int swz = (col & 7) << 3;
    const int ro0 = col * 64 + ((g * 8) ^ swz);
    const int ro1 = col * 64 + ((32 + g * 8) ^ swz);

    #pragma unroll 2
    for (int c = 0; c < NCHUNK; ++c) {
        // T14 issue-early: next chunk's loads start before this chunk's compute
        short8 nA, nB; float hn[4];
        if (c < NCHUNK - 1) {
            nA = gB[(size_t)(c + 1) * 512 + t * 2];
            nB = gB[(size_t)(c + 1) * 512 + t * 2 + 1];
            #pragma unroll
            for (int q = 0; q < 4; ++q) hn[q] = he2g[(c + 1) * 64 + q * 16 + col];
        }

        const short* Lb = lbs[c & 1];
        #pragma unroll
        for (int cp = 0; cp < 2; ++cp) {            // ct pairs -> min3 fusion
            const int ct0 = cp * 2, ct1 = cp * 2 + 1;
            short8 b00 = *(const short8*)(Lb + ct0 * 1024 + ro0);
            short8 b01 = *(const short8*)(Lb + ct0 * 1024 + ro1);
            short8 b10 = *(const short8*)(Lb + ct1 * 1024 + ro0);
            short8 b11 = *(const short8*)(Lb + ct1 * 1024 + ro1);
            const unsigned code0 = (unsigned)(c * 64 + ct0 * 16 + col);
            const unsigned code1 = code0 + 16;
            f32x4 hv0 = {hcur[ct0], hcur[ct0], hcur[ct0], hcur[ct0]};
            f32x4 hv1 = {hcur[ct1], hcur[ct1], hcur[ct1], hcur[ct1]};
            #pragma unroll
            for (int rt = 0; rt < 2; ++rt) {
                f32x4 a0 = __builtin_amdgcn_mfma_f32_16x16x32_bf16(af[rt][0], b00, hv0, 0, 0, 0);
                a0 = __builtin_amdgcn_mfma_f32_16x16x32_bf16(af[rt][1], b01, a0, 0, 0, 0);
                f32x4 a1 = __builtin_amdgcn_mfma_f32_16x16x32_bf16(af[rt][0], b10, hv1, 0, 0, 0);
                a1 = __builtin_amdgcn_mfma_f32_16x16x32_bf16(af[rt][1], b11, a1, 0, 0, 0);
                #pragma unroll
                for (int r = 0; r < 4; ++r) {
                    union { float f; unsigned u; } m0, m1;
                    m0.f = a0[r]; m0.u = (m0.u & 0xFFFFFC00u) | code0;  // v_and_or_b32
                    m1.f = a1[r]; m1.u = (m1.u & 0xFFFFFC00u) | code1;
                    pk[rt][r] = fminf(fminf(pk[rt][r], m0.f), m1.f);    // -> v_min3_f32
                }
            }
        }

        // T14 write-late: land next chunk after compute; barrier drains (vmcnt+lgkm)
        if (c < NCHUNK - 1) {
            short* Ld = (short*)lbs[(c & 1) ^ 1];
            ((short8*)Ld)[t * 2]     = nA;
            ((short8*)Ld)[t * 2 + 1] = nB;
            #pragma unroll
            for (int q = 0; q < 4; ++q) hcur[q] = hn[q];
        }
        __syncthreads();
    }

    // ---- butterfly min over 16 code-columns (all lanes end with row's answer) ----
    #pragma unroll
    for (int rt = 0; rt < 2; ++rt) {
        #pragma unroll
        for (int r = 0; r < 4; ++r) {
            float d = pk[rt][r];
            #pragma unroll
            for (int mask = 1; mask < 16; mask <<= 1)
                d = fminf(d, __shfl_xor(d, mask, 64));
            pk[rt][r] = d;
        }
    }

    // ---- epilogue: output = E rows (k in-register), loss from scores ----
    float lsum = z2;
    const int rowbase = n0 + wid * WROWS;
    #pragma unroll
    for (int rt = 0; rt < 2; ++rt) {
        #pragma unroll
        for (int r = 0; r < 4; ++r) {
            union { float f; unsigned u; } b; b.f = pk[rt][r];
            unsigned kk = b.u & 1023u;
            if (col == 0) {                              // count each row's score once
                union { unsigned u; float f; } sc; sc.u = b.u & 0xFFFFFC00u;
                lsum += 2.0f * (sc.f - 1.0f);            // ||e||^2 - 2 z.e
            }
            int row = rt * 16 + g * 4 + r;
            float4 qv = *(const float4*)(E + (size_t)kk * 64 + col * 4);
            *(float4*)(out + ((size_t)(rowbase + row)) * 64 + col * 4) = qv;
        }
    }

    #pragma unroll
    for (int off = 32; off >= 1; off >>= 1) lsum += __shfl_down(lsum, off, 64);
    if (lane == 0) wsum[wid] = lsum;
    __syncthreads();
    if (t == 0) partial[blk] = (wsum[0] + wsum[1]) + (wsum[2] + wsum[3]);
}

// ---------- fallback fp32 path (round-1, correctness-proven) ----------
__global__ __launch_bounds__(64) void vq_init(float* out) {
    if (threadIdx.x == 0) { out[NDTOT] = 0.0f; out[NDTOT + 1] = 0.0f; }
}

__global__ __launch_bounds__(256, 4) void vq_main_fp32(const float* __restrict__ z,
                                                       const float* __restrict__ E,
                                                       float* __restrict__ out,
                                                       float* __restrict__ partial) {
    __shared__ float zs[64][65];
    __shared__ float e2s[KCB];
    __shared__ float wmin[4][64];
    __shared__ int   widx[4][64];
    __shared__ int   rowidx[64];
    __shared__ float wsum[4];

    const int t   = threadIdx.x;
    const int blk = blockIdx.x;
    const int n0  = blk << 6;
    const int bb  = n0 >> 12;
    const int hw0 = n0 & 4095;
    const float* zb = z + (size_t)bb * CCH * HWSZ + hw0;

    #pragma unroll
    for (int j = 0; j < 16; ++j) {
        int f = t + 256 * j;
        int c = f >> 6, i = f & 63;
        zs[c][i] = zb[(size_t)c * HWSZ + i];
    }
    for (int qq = t; qq < KCB; qq += 256) {
        const float4* ep = (const float4*)(E + (size_t)qq * 64);
        float s0 = 0.f;
        #pragma unroll
        for (int c4 = 0; c4 < 16; ++c4) {
            float4 a = ep[c4];
            s0 += a.x * a.x + a.y * a.y + a.z * a.z + a.w * a.w;
        }
        e2s[qq] = s0;
    }
    __syncthreads();

    const int i   = t & 63;
    const int wid = t >> 6;
    float zr[64];
    #pragma unroll
    for (int c = 0; c < 64; ++c) zr[c] = zs[c][i];

    float best = 3.4e38f;
    int   bi = 0;
    const int k0 = wid << 8;
    const float* Ew = E + (size_t)k0 * 64;
    for (int kk = 0; kk < 256; ++kk) {
        const float4* ek = (const float4*)(Ew + (size_t)kk * 64);
        float d0 = 0.f, d1 = 0.f, d2 = 0.f, d3 = 0.f;
        #pragma unroll
        for (int c4 = 0; c4 < 16; ++c4) {
            float4 a = ek[c4];
            d0 = fmaf(a.x, zr[4 * c4 + 0], d0);
            d1 = fmaf(a.y, zr[4 * c4 + 1], d1);
            d2 = fmaf(a.z, zr[4 * c4 + 2], d2);
            d3 = fmaf(a.w, zr[4 * c4 + 3], d3);
        }
        float dot  = (d0 + d1) + (d2 + d3);
        float dist = fmaf(-2.0f, dot, e2s[k0 + kk]);
        if (dist < best) { best = dist; bi = k0 + kk; }
    }
    wmin[wid][i] = best; widx[wid][i] = bi;
    __syncthreads();
    if (t < 64) {
        float m = wmin[0][t]; int ix = widx[0][t];
        #pragma unroll
        for (int w = 1; w < 4; ++w) {
            float v = wmin[w][t]; int x = widx[w][t];
            if (v < m) { m = v; ix = x; }
        }
        rowidx[t] = ix;
    }
    __syncthreads();

    float lsum = 0.f;
    const size_t base = (size_t)blk * 4096;
    float* oflat = out + base;
    #pragma unroll
    for (int j = 0; j < 16; ++j) {
        int f  = t + 256 * j;
        int nl = f >> 6, d = f & 63;
        int k  = rowidx[nl];
        float qv = E[(size_t)k * 64 + d];
        float zf = zs[d][nl];
        float df = qv - zf;
        lsum += df * df;
        oflat[f] = qv;
    }
    #pragma unroll
    for (int off = 32; off >= 1; off >>= 1) lsum += __shfl_down(lsum, off, 64);
    if (i == 0) wsum[wid] = lsum;
    __syncthreads();
    if (t == 0) {
        float s = (wsum[0] + wsum[1]) + (wsum[2] + wsum[3]);
        if (partial) partial[blk] = s;
        else         atomicAdd(&out[NDTOT + 1], s);
    }
}

__global__ __launch_bounds__(256) void vq_fin(const float* __restrict__ partial,
                                              float* __restrict__ out, int npart) {
    if (npart > 0) {
        __shared__ float ps[256];
        float s = 0.f;
        for (int qq = threadIdx.x; qq < npart; qq += 256) s += partial[qq];
        ps[threadIdx.x] = s;
        __syncthreads();
        for (int st = 128; st >= 1; st >>= 1) {
            if (threadIdx.x < st) ps[threadIdx.x] += ps[threadIdx.x + st];
            __syncthreads();
        }
        if (threadIdx.x == 0) {
            float mse = ps[0] / (float)NDTOT;
            out[NDTOT]     = 0.25f * mse;   // commitment_loss
            out[NDTOT + 1] = mse;           // codebook_loss
        }
    } else {
        if (threadIdx.x == 0) {
            float mse = out[NDTOT + 1] / (float)NDTOT;
            out[NDTOT]     = 0.25f * mse;
            out[NDTOT + 1] = mse;
        }
    }
}

extern "C" void kernel_launch(void* const* d_in, const int* in_sizes, int n_in,
                              void* d_out, int out_size, void* d_ws, size_t ws_size,
                              hipStream_t stream) {
    const float* z = (const float*)d_in[0];
    const float* E = (const float*)d_in[1];
    float* out = (float*)d_out;

    const size_t EBF_BYTES = (size_t)KCB * 64 * 2;                 // 131072
    const size_t need = EBF_BYTES + 4096 + MBLK * sizeof(float);   // Ebf + he2b + partial

    if (ws_size >= need) {
        unsigned* EbfU = (unsigned*)d_ws;
        short* Ebf  = (short*)d_ws;
        float* he2b = (float*)((char*)d_ws + EBF_BYTES);
        float* partial = (float*)((char*)d_ws + EBF_BYTES + 4096);
        hipLaunchKernelGGL(vq_prep, dim3(4), dim3(256), 0, stream, E, EbfU, he2b);
        hipLaunchKernelGGL(vq_mfma, dim3(MBLK), dim3(256), 0, stream,
                           z, E, Ebf, he2b, out, partial);
        hipLaunchKernelGGL(vq_fin, dim3(1), dim3(256), 0, stream, partial, out, MBLK);
    } else {
        float* partial = (ws_size >= KCB * sizeof(float)) ? (float*)d_ws : nullptr;
        int npart = (partial != nullptr) ? KCB : 0;
        hipLaunchKernelGGL(vq_init, dim3(1), dim3(64), 0, stream, out);
        hipLaunchKernelGGL(vq_main_fp32, dim3(1024), dim3(256), 0, stream, z, E, out, partial);
        hipLaunchKernelGGL(vq_fin, dim3(1), dim3(256), 0, stream, partial, out, npart);
    }
}